// Round 1
// baseline (1235.418 us; speedup 1.0000x reference)
//
#include <hip/hip_runtime.h>
#include <cstdint>

#define C_DIM 256
#define EPS 1e-5f
#define BM 64
#define BN 64
#define BK 16

// ---------------- setup kernels ----------------
__global__ void k_init(int* cnt, int* cursor, int n) {
  int i = blockIdx.x * blockDim.x + threadIdx.x;
  if (i < n) { cnt[i] = 0; cursor[i] = 0; }
}

__global__ void k_count(const int* __restrict__ col, int E, int* cnt) {
  int e = blockIdx.x * blockDim.x + threadIdx.x;
  if (e < E) atomicAdd(&cnt[col[e]], 1);
}

__global__ void k_isd(const int* __restrict__ cnt, float* isd, int n) {
  int i = blockIdx.x * blockDim.x + threadIdx.x;
  if (i < n) isd[i] = rsqrtf((float)(cnt[i] + 1));  // +1 = self-loop
}

// 3-pass exclusive scan over cnt -> row_ptr (N up to 1024*1024)
__global__ void k_scan1(const int* __restrict__ cnt, int* excl, int* bsum, int n) {
  __shared__ int s[1024];
  int i = blockIdx.x * 1024 + threadIdx.x;
  int v = (i < n) ? cnt[i] : 0;
  s[threadIdx.x] = v;
  __syncthreads();
  for (int off = 1; off < 1024; off <<= 1) {
    int t = (threadIdx.x >= off) ? s[threadIdx.x - off] : 0;
    __syncthreads();
    s[threadIdx.x] += t;
    __syncthreads();
  }
  if (i < n) excl[i] = s[threadIdx.x] - v;
  if (threadIdx.x == 1023) bsum[blockIdx.x] = s[1023];
}

__global__ void k_scan2(int* bsum, int nb) {
  __shared__ int s[1024];
  int v = (threadIdx.x < nb) ? bsum[threadIdx.x] : 0;
  s[threadIdx.x] = v;
  __syncthreads();
  for (int off = 1; off < 1024; off <<= 1) {
    int t = (threadIdx.x >= off) ? s[threadIdx.x - off] : 0;
    __syncthreads();
    s[threadIdx.x] += t;
    __syncthreads();
  }
  if (threadIdx.x < nb) bsum[threadIdx.x] = s[threadIdx.x] - v;  // exclusive
}

__global__ void k_scan3(int* excl, const int* __restrict__ bsum, int n, int E) {
  int i = blockIdx.x * 1024 + threadIdx.x;
  if (i < n) excl[i] += bsum[blockIdx.x];
  if (i == 0) excl[n] = E;
}

__global__ void k_fill(const int* __restrict__ row, const int* __restrict__ col, int E,
                       const int* __restrict__ row_ptr, int* cursor,
                       const float* __restrict__ isd,
                       int* __restrict__ srcs, float* __restrict__ nrm) {
  int e = blockIdx.x * blockDim.x + threadIdx.x;
  if (e < E) {
    int d = col[e], s = row[e];
    int p = row_ptr[d] + atomicAdd(&cursor[d], 1);
    srcs[p] = s;
    nrm[p] = isd[s] * isd[d];
  }
}

// ---------------- fp32 tiled GEMM: Cout[M,256] = A[M,256] @ W[256,256] ----------------
__global__ __launch_bounds__(256) void k_gemm(const float* __restrict__ A,
                                              const float* __restrict__ W,
                                              float* __restrict__ Cout, int M) {
  __shared__ float As[BK][BM + 4];  // stride 68 floats: 16B-aligned rows, breaks pow2 banks
  __shared__ float Bs[BK][BN + 4];
  int tid = threadIdx.x;
  int bm = blockIdx.y * BM;
  int bn = blockIdx.x * BN;
  int ty = tid >> 4, tx = tid & 15;
  float acc[4][4] = {};

  for (int k0 = 0; k0 < C_DIM; k0 += BK) {
    // A tile: thread t -> A[bm + t/4][k0 + (t%4)*4 .. +3], transposed into As[k][m]
    {
      int r = tid >> 2, c = (tid & 3) * 4;
      int gm = bm + r; if (gm >= M) gm = M - 1;
      const float4 av = *(const float4*)&A[(size_t)gm * C_DIM + k0 + c];
      As[c + 0][r] = av.x; As[c + 1][r] = av.y; As[c + 2][r] = av.z; As[c + 3][r] = av.w;
      // B tile: thread t -> W[k0 + t/16][bn + (t%16)*4 .. +3]
      int br = tid >> 4, bc = (tid & 15) * 4;
      *(float4*)&Bs[br][bc] = *(const float4*)&W[(size_t)(k0 + br) * C_DIM + bn + bc];
    }
    __syncthreads();
#pragma unroll
    for (int k = 0; k < BK; k++) {
      float4 a = *(const float4*)&As[k][ty * 4];
      float4 b = *(const float4*)&Bs[k][tx * 4];
      acc[0][0] += a.x * b.x; acc[0][1] += a.x * b.y; acc[0][2] += a.x * b.z; acc[0][3] += a.x * b.w;
      acc[1][0] += a.y * b.x; acc[1][1] += a.y * b.y; acc[1][2] += a.y * b.z; acc[1][3] += a.y * b.w;
      acc[2][0] += a.z * b.x; acc[2][1] += a.z * b.y; acc[2][2] += a.z * b.z; acc[2][3] += a.z * b.w;
      acc[3][0] += a.w * b.x; acc[3][1] += a.w * b.y; acc[3][2] += a.w * b.z; acc[3][3] += a.w * b.w;
    }
    __syncthreads();
  }
#pragma unroll
  for (int i = 0; i < 4; i++) {
    int m = bm + ty * 4 + i;
    if (m < M) {
      float4 o = make_float4(acc[i][0], acc[i][1], acc[i][2], acc[i][3]);
      *(float4*)&Cout[(size_t)m * C_DIM + bn + tx * 4] = o;
    }
  }
}

// ---------------- fused aggregate + bias + LayerNorm + ReLU (1 wave per node) ----------------
__global__ __launch_bounds__(256) void k_agg_ln(const float* __restrict__ xw,
    const int* __restrict__ row_ptr, const int* __restrict__ srcs,
    const float* __restrict__ nrm, const float* __restrict__ isd,
    const float* __restrict__ bias, const float* __restrict__ gamma,
    const float* __restrict__ beta, float* __restrict__ out, int n) {
  int wave = blockIdx.x * 4 + (threadIdx.x >> 6);
  int lane = threadIdx.x & 63;
  if (wave >= n) return;
  int i = wave;

  float si = isd[i];
  float sn = si * si;  // self-loop norm
  float4 acc = ((const float4*)&xw[(size_t)i * C_DIM])[lane];
  acc.x *= sn; acc.y *= sn; acc.z *= sn; acc.w *= sn;

  int e0 = row_ptr[i], e1 = row_ptr[i + 1];
  int e = e0;
  for (; e + 1 < e1; e += 2) {  // 2-way unroll: two independent row loads in flight
    int s0 = srcs[e], s1 = srcs[e + 1];
    float w0 = nrm[e], w1 = nrm[e + 1];
    float4 v0 = ((const float4*)&xw[(size_t)s0 * C_DIM])[lane];
    float4 v1 = ((const float4*)&xw[(size_t)s1 * C_DIM])[lane];
    acc.x += v0.x * w0 + v1.x * w1;
    acc.y += v0.y * w0 + v1.y * w1;
    acc.z += v0.z * w0 + v1.z * w1;
    acc.w += v0.w * w0 + v1.w * w1;
  }
  if (e < e1) {
    int s0 = srcs[e];
    float w0 = nrm[e];
    float4 v0 = ((const float4*)&xw[(size_t)s0 * C_DIM])[lane];
    acc.x += v0.x * w0; acc.y += v0.y * w0; acc.z += v0.z * w0; acc.w += v0.w * w0;
  }

  float4 bv = ((const float4*)bias)[lane];
  acc.x += bv.x; acc.y += bv.y; acc.z += bv.z; acc.w += bv.w;

  float sum = acc.x + acc.y + acc.z + acc.w;
  float sq  = acc.x * acc.x + acc.y * acc.y + acc.z * acc.z + acc.w * acc.w;
#pragma unroll
  for (int off = 32; off >= 1; off >>= 1) {
    sum += __shfl_xor(sum, off, 64);
    sq  += __shfl_xor(sq,  off, 64);
  }
  float mu  = sum * (1.0f / C_DIM);
  float var = sq * (1.0f / C_DIM) - mu * mu;
  float rs  = rsqrtf(var + EPS);

  float4 g  = ((const float4*)gamma)[lane];
  float4 bt = ((const float4*)beta)[lane];
  float4 o;
  o.x = fmaxf((acc.x - mu) * rs * g.x + bt.x, 0.0f);
  o.y = fmaxf((acc.y - mu) * rs * g.y + bt.y, 0.0f);
  o.z = fmaxf((acc.z - mu) * rs * g.z + bt.z, 0.0f);
  o.w = fmaxf((acc.w - mu) * rs * g.w + bt.w, 0.0f);
  ((float4*)&out[(size_t)i * C_DIM])[lane] = o;
}

// ---------------- host ----------------
extern "C" void kernel_launch(void* const* d_in, const int* in_sizes, int n_in,
                              void* d_out, int out_size, void* d_ws, size_t ws_size,
                              hipStream_t stream) {
  const float* x     = (const float*)d_in[0];
  const int*   edges = (const int*)d_in[1];
  const float* W1    = (const float*)d_in[2];
  const float* b1    = (const float*)d_in[3];
  const float* W2    = (const float*)d_in[4];
  const float* b2    = (const float*)d_in[5];
  const float* gamma = (const float*)d_in[6];
  const float* beta  = (const float*)d_in[7];

  int N = in_sizes[0] / C_DIM;
  int E = in_sizes[1] / 2;
  const int* row = edges;
  const int* col = edges + E;

  char* ws = (char*)d_ws;
  size_t off = 0;
  auto alloc = [&](size_t bytes) -> void* {
    void* p = ws + off;
    off = (off + bytes + 255) & ~(size_t)255;
    return p;
  };
  float* xw      = (float*)alloc((size_t)N * C_DIM * 4);
  int*   cnt     = (int*)alloc((size_t)N * 4);
  int*   cursor  = (int*)alloc((size_t)N * 4);
  float* isd     = (float*)alloc((size_t)N * 4);
  int*   row_ptr = (int*)alloc((size_t)(N + 1) * 4);
  int nb = (N + 1023) / 1024;
  int*   bsum    = (int*)alloc((size_t)nb * 4);
  int*   srcs    = (int*)alloc((size_t)E * 4);
  float* nrm     = (float*)alloc((size_t)E * 4);

  float* z1 = (float*)d_out;
  float* z2 = (float*)d_out + (size_t)N * C_DIM;

  // CSR build (shared by both layers)
  k_init <<<(N + 255) / 256, 256, 0, stream>>>(cnt, cursor, N);
  k_count<<<(E + 255) / 256, 256, 0, stream>>>(col, E, cnt);
  k_isd  <<<(N + 255) / 256, 256, 0, stream>>>(cnt, isd, N);
  k_scan1<<<nb, 1024, 0, stream>>>(cnt, row_ptr, bsum, N);
  k_scan2<<<1, 1024, 0, stream>>>(bsum, nb);
  k_scan3<<<nb, 1024, 0, stream>>>(row_ptr, bsum, N, E);
  k_fill <<<(E + 255) / 256, 256, 0, stream>>>(row, col, E, row_ptr, cursor, isd, srcs, nrm);

  dim3 ggrid(C_DIM / BN, (N + BM - 1) / BM);
  int agg_blocks = (N + 3) / 4;  // 1 wave per node, 4 waves per block

  // layer 1
  k_gemm  <<<ggrid, 256, 0, stream>>>(x, W1, xw, N);
  k_agg_ln<<<agg_blocks, 256, 0, stream>>>(xw, row_ptr, srcs, nrm, isd, b1, gamma, beta, z1, N);
  // layer 2
  k_gemm  <<<ggrid, 256, 0, stream>>>(z1, W2, xw, N);
  k_agg_ln<<<agg_blocks, 256, 0, stream>>>(xw, row_ptr, srcs, nrm, isd, b2, gamma, beta, z2, N);
}

// Round 2
// 779.842 us; speedup vs baseline: 1.5842x; 1.5842x over previous
//
#include <hip/hip_runtime.h>
#include <cstdint>

#define C_DIM 256
#define EPS 1e-5f

typedef __attribute__((ext_vector_type(8))) short short8;
typedef __attribute__((ext_vector_type(4))) float f32x4;

__device__ __forceinline__ ushort f2bf(float f) {
  uint32_t u = __float_as_uint(f);
  u = (u + 0x7fffu + ((u >> 16) & 1u)) >> 16;
  return (ushort)u;
}
__device__ __forceinline__ float bflo(uint32_t p) { return __uint_as_float(p << 16); }
__device__ __forceinline__ float bfhi(uint32_t p) { return __uint_as_float(p & 0xffff0000u); }

// ---------------- setup kernels ----------------
__global__ void k_init(int* cnt, int n) {
  int i = blockIdx.x * blockDim.x + threadIdx.x;
  if (i < n) cnt[i] = 0;
}

__global__ void k_count(const int* __restrict__ col, int E, int* cnt) {
  int e = blockIdx.x * blockDim.x + threadIdx.x;
  if (e < E) atomicAdd(&cnt[col[e]], 1);
}

// reads cnt -> isd, then zeroes cnt so it can be reused as the fill cursor
__global__ void k_isd(int* cnt, float* isd, int n) {
  int i = blockIdx.x * blockDim.x + threadIdx.x;
  if (i < n) { isd[i] = rsqrtf((float)(cnt[i] + 1)); cnt[i] = 0; }
}

__global__ void k_scan1(const int* __restrict__ cnt, int* excl, int* bsum, int n) {
  __shared__ int s[1024];
  int i = blockIdx.x * 1024 + threadIdx.x;
  int v = (i < n) ? cnt[i] : 0;
  s[threadIdx.x] = v;
  __syncthreads();
  for (int off = 1; off < 1024; off <<= 1) {
    int t = (threadIdx.x >= off) ? s[threadIdx.x - off] : 0;
    __syncthreads();
    s[threadIdx.x] += t;
    __syncthreads();
  }
  if (i < n) excl[i] = s[threadIdx.x] - v;
  if (threadIdx.x == 1023) bsum[blockIdx.x] = s[1023];
}

__global__ void k_scan2(int* bsum, int nb) {
  __shared__ int s[1024];
  int v = (threadIdx.x < nb) ? bsum[threadIdx.x] : 0;
  s[threadIdx.x] = v;
  __syncthreads();
  for (int off = 1; off < 1024; off <<= 1) {
    int t = (threadIdx.x >= off) ? s[threadIdx.x - off] : 0;
    __syncthreads();
    s[threadIdx.x] += t;
    __syncthreads();
  }
  if (threadIdx.x < nb) bsum[threadIdx.x] = s[threadIdx.x] - v;
}

__global__ void k_scan3(int* excl, const int* __restrict__ bsum, int n, int E) {
  int i = blockIdx.x * 1024 + threadIdx.x;
  if (i < n) excl[i] += bsum[blockIdx.x];
  if (i == 0) excl[n] = E;
}

__global__ void k_fill(const int* __restrict__ row, const int* __restrict__ col, int E,
                       const int* __restrict__ row_ptr, int* cursor,
                       const float* __restrict__ isd,
                       int* __restrict__ srcs, float* __restrict__ nrm) {
  int e = blockIdx.x * blockDim.x + threadIdx.x;
  if (e < E) {
    int d = col[e], s = row[e];
    int p = row_ptr[d] + atomicAdd(&cursor[d], 1);
    srcs[p] = s;
    nrm[p] = isd[s] * isd[d];
  }
}

__global__ void k_cvt_x(const float* __restrict__ x, ushort* __restrict__ xb, int n4) {
  int i = blockIdx.x * blockDim.x + threadIdx.x;
  if (i < n4) {
    float4 v = ((const float4*)x)[i];
    ushort4 o;
    o.x = f2bf(v.x); o.y = f2bf(v.y); o.z = f2bf(v.z); o.w = f2bf(v.w);
    ((ushort4*)xb)[i] = o;
  }
}

// W [K][N] fp32 -> Wt [N][K] bf16, for both layer weights
__global__ void k_cvt_w(const float* __restrict__ W1, const float* __restrict__ W2,
                        ushort* __restrict__ Wt1, ushort* __restrict__ Wt2) {
  int i = blockIdx.x * blockDim.x + threadIdx.x;  // output index [n][k]
  int n = i >> 8, k = i & 255;
  Wt1[i] = f2bf(W1[k * 256 + n]);
  Wt2[i] = f2bf(W2[k * 256 + n]);
}

// ---------------- bf16 MFMA GEMM: Cb[M,256] = A[M,256] @ Wt^T ----------------
// m97 structure: 128x128 tile, BK=64, global_load_lds width-16, 16x16x32 MFMA.
// LDS chunk-XOR swizzle (16B chunks, chunk(r,c) stored at slot c^(r&7)) keeps
// both the wave-uniform global_load_lds staging AND the ds_read_b128 frag
// reads 2-way-max on banks (2-way is free, m136).
__global__ __launch_bounds__(256) void k_gemm_bf16(const ushort* __restrict__ A,
                                                   const ushort* __restrict__ Wt,
                                                   ushort* __restrict__ Cb, int M) {
  __shared__ ushort As[128 * 64];
  __shared__ ushort Bs[128 * 64];
  const int tid = threadIdx.x;
  const int wave = tid >> 6, lane = tid & 63;
  const int bm = blockIdx.x * 128;
  const int bn = blockIdx.y * 128;
  const int wm = (wave >> 1) * 64, wn = (wave & 1) * 64;

  f32x4 acc[4][4] = {};

  const int r_off = lane >> 3;  // 0..7 rows per 1KB staging inst
  const int cc = lane & 7;      // 16B chunk slot within row

  for (int k0 = 0; k0 < C_DIM; k0 += 64) {
#pragma unroll
    for (int j = 0; j < 4; j++) {
      int rl = wave * 32 + j * 8 + r_off;  // tile row 0..127
      int c = cc ^ (rl & 7);               // swizzled source chunk
      int gm = bm + rl; if (gm >= M) gm = M - 1;
      const ushort* ga = &A[(size_t)gm * C_DIM + k0 + c * 8];
      ushort* la = &As[(size_t)(wave * 32 + j * 8) * 64];
      __builtin_amdgcn_global_load_lds((const __attribute__((address_space(1))) void*)ga,
                                       (__attribute__((address_space(3))) void*)la, 16, 0, 0);
      const ushort* gb = &Wt[(size_t)(bn + rl) * C_DIM + k0 + c * 8];
      ushort* lb = &Bs[(size_t)(wave * 32 + j * 8) * 64];
      __builtin_amdgcn_global_load_lds((const __attribute__((address_space(1))) void*)gb,
                                       (__attribute__((address_space(3))) void*)lb, 16, 0, 0);
    }
    __syncthreads();
#pragma unroll
    for (int s = 0; s < 2; s++) {
      short8 af[4], bfr[4];
#pragma unroll
      for (int t = 0; t < 4; t++) {
        int ra = wm + t * 16 + (lane & 15);
        int ca = s * 4 + (lane >> 4);
        af[t] = *(const short8*)&As[ra * 64 + ((ca ^ (ra & 7)) << 3)];
        int rb = wn + t * 16 + (lane & 15);
        bfr[t] = *(const short8*)&Bs[rb * 64 + ((ca ^ (rb & 7)) << 3)];
      }
#pragma unroll
      for (int mt = 0; mt < 4; mt++)
#pragma unroll
        for (int nt = 0; nt < 4; nt++)
          acc[mt][nt] = __builtin_amdgcn_mfma_f32_16x16x32_bf16(af[mt], bfr[nt], acc[mt][nt], 0, 0, 0);
    }
    __syncthreads();
  }

  // epilogue: C/D layout col=lane&15, row=(lane>>4)*4+reg (m89-verified)
#pragma unroll
  for (int mt = 0; mt < 4; mt++) {
#pragma unroll
    for (int nt = 0; nt < 4; nt++) {
      int col = bn + wn + nt * 16 + (lane & 15);
      int row0 = bm + wm + mt * 16 + ((lane >> 4) << 2);
#pragma unroll
      for (int r = 0; r < 4; r++) {
        int row = row0 + r;
        if (row < M) Cb[(size_t)row * C_DIM + col] = f2bf(acc[mt][nt][r]);
      }
    }
  }
}

// ---------------- fused aggregate(bf16 gather) + bias + LN + ReLU ----------------
__global__ __launch_bounds__(256) void k_agg_ln(const ushort* __restrict__ xwb,
    const int* __restrict__ row_ptr, const int* __restrict__ srcs,
    const float* __restrict__ nrm, const float* __restrict__ isd,
    const float* __restrict__ bias, const float* __restrict__ gamma,
    const float* __restrict__ beta, float* __restrict__ out,
    ushort* __restrict__ outb, int n) {
  int i = blockIdx.x * 4 + (threadIdx.x >> 6);
  int lane = threadIdx.x & 63;
  if (i >= n) return;
  const uint2* xw2 = (const uint2*)xwb;  // 8B = 4 bf16 channels per lane

  float si = isd[i];
  float sn = si * si;
  uint2 p = xw2[(size_t)i * 64 + lane];
  float a0 = bflo(p.x) * sn, a1 = bfhi(p.x) * sn;
  float a2 = bflo(p.y) * sn, a3 = bfhi(p.y) * sn;

  int e0 = row_ptr[i], e1 = row_ptr[i + 1];
  int e = e0;
  for (; e + 1 < e1; e += 2) {
    int s0 = srcs[e], s1 = srcs[e + 1];
    float w0 = nrm[e], w1 = nrm[e + 1];
    uint2 v0 = xw2[(size_t)s0 * 64 + lane];
    uint2 v1 = xw2[(size_t)s1 * 64 + lane];
    a0 += bflo(v0.x) * w0 + bflo(v1.x) * w1;
    a1 += bfhi(v0.x) * w0 + bfhi(v1.x) * w1;
    a2 += bflo(v0.y) * w0 + bflo(v1.y) * w1;
    a3 += bfhi(v0.y) * w0 + bfhi(v1.y) * w1;
  }
  if (e < e1) {
    int s0 = srcs[e];
    float w0 = nrm[e];
    uint2 v0 = xw2[(size_t)s0 * 64 + lane];
    a0 += bflo(v0.x) * w0; a1 += bfhi(v0.x) * w0;
    a2 += bflo(v0.y) * w0; a3 += bfhi(v0.y) * w0;
  }

  float4 bv = ((const float4*)bias)[lane];
  a0 += bv.x; a1 += bv.y; a2 += bv.z; a3 += bv.w;

  float sum = a0 + a1 + a2 + a3;
  float sq = a0 * a0 + a1 * a1 + a2 * a2 + a3 * a3;
#pragma unroll
  for (int off = 32; off >= 1; off >>= 1) {
    sum += __shfl_xor(sum, off, 64);
    sq += __shfl_xor(sq, off, 64);
  }
  float mu = sum * (1.0f / C_DIM);
  float var = sq * (1.0f / C_DIM) - mu * mu;
  float rs = rsqrtf(var + EPS);

  float4 g = ((const float4*)gamma)[lane];
  float4 bt = ((const float4*)beta)[lane];
  float4 o;
  o.x = fmaxf((a0 - mu) * rs * g.x + bt.x, 0.0f);
  o.y = fmaxf((a1 - mu) * rs * g.y + bt.y, 0.0f);
  o.z = fmaxf((a2 - mu) * rs * g.z + bt.z, 0.0f);
  o.w = fmaxf((a3 - mu) * rs * g.w + bt.w, 0.0f);
  ((float4*)out)[(size_t)i * 64 + lane] = o;

  if (outb) {  // bf16 copy feeding next layer's GEMM
    uint2 q;
    q.x = (uint32_t)f2bf(o.x) | ((uint32_t)f2bf(o.y) << 16);
    q.y = (uint32_t)f2bf(o.z) | ((uint32_t)f2bf(o.w) << 16);
    ((uint2*)outb)[(size_t)i * 64 + lane] = q;
  }
}

// ---------------- host ----------------
extern "C" void kernel_launch(void* const* d_in, const int* in_sizes, int n_in,
                              void* d_out, int out_size, void* d_ws, size_t ws_size,
                              hipStream_t stream) {
  const float* x = (const float*)d_in[0];
  const int* edges = (const int*)d_in[1];
  const float* W1 = (const float*)d_in[2];
  const float* b1 = (const float*)d_in[3];
  const float* W2 = (const float*)d_in[4];
  const float* b2 = (const float*)d_in[5];
  const float* gamma = (const float*)d_in[6];
  const float* beta = (const float*)d_in[7];

  int N = in_sizes[0] / C_DIM;
  int E = in_sizes[1] / 2;
  const int* row = edges;
  const int* col = edges + E;

  char* ws = (char*)d_ws;
  size_t off = 0;
  auto alloc = [&](size_t bytes) -> void* {
    void* p = ws + off;
    off = (off + bytes + 255) & ~(size_t)255;
    return p;
  };
  ushort* xwb = (ushort*)alloc((size_t)N * C_DIM * 2);  // GEMM output, bf16
  ushort* xb  = (ushort*)alloc((size_t)N * C_DIM * 2);  // layer-1 A; aliased as z1-bf16 after agg1
  ushort* Wt1 = (ushort*)alloc(65536 * 2);
  ushort* Wt2 = (ushort*)alloc(65536 * 2);
  int* cnt = (int*)alloc((size_t)N * 4);                 // reused as fill cursor
  float* isd = (float*)alloc((size_t)N * 4);
  int* row_ptr = (int*)alloc((size_t)(N + 1) * 4);
  int nb = (N + 1023) / 1024;
  int* bsum = (int*)alloc((size_t)nb * 4);
  int* srcs = (int*)alloc((size_t)E * 4);
  float* nrm = (float*)alloc((size_t)E * 4);

  float* z1 = (float*)d_out;
  float* z2 = (float*)d_out + (size_t)N * C_DIM;

  // conversions
  int n4 = N * C_DIM / 4;
  k_cvt_x<<<(n4 + 255) / 256, 256, 0, stream>>>(x, xb, n4);
  k_cvt_w<<<256, 256, 0, stream>>>(W1, W2, Wt1, Wt2);

  // CSR build (shared by both layers)
  k_init<<<(N + 255) / 256, 256, 0, stream>>>(cnt, N);
  k_count<<<(E + 255) / 256, 256, 0, stream>>>(col, E, cnt);
  k_scan1<<<nb, 1024, 0, stream>>>(cnt, row_ptr, bsum, N);
  k_scan2<<<1, 1024, 0, stream>>>(bsum, nb);
  k_scan3<<<nb, 1024, 0, stream>>>(row_ptr, bsum, N, E);
  k_isd<<<(N + 255) / 256, 256, 0, stream>>>(cnt, isd, N);  // zeroes cnt -> cursor
  k_fill<<<(E + 255) / 256, 256, 0, stream>>>(row, col, E, row_ptr, cnt, isd, srcs, nrm);

  dim3 ggrid((N + 127) / 128, 2);
  int agg_blocks = (N + 3) / 4;

  // layer 1
  k_gemm_bf16<<<ggrid, 256, 0, stream>>>(xb, Wt1, xwb, N);
  k_agg_ln<<<agg_blocks, 256, 0, stream>>>(xwb, row_ptr, srcs, nrm, isd, b1, gamma, beta, z1, xb, N);
  // layer 2 (xb now holds z1 in bf16)
  k_gemm_bf16<<<ggrid, 256, 0, stream>>>(xb, Wt2, xwb, N);
  k_agg_ln<<<agg_blocks, 256, 0, stream>>>(xwb, row_ptr, srcs, nrm, isd, b2, gamma, beta, z2, nullptr, N);
}

// Round 3
// 738.748 us; speedup vs baseline: 1.6723x; 1.0556x over previous
//
#include <hip/hip_runtime.h>
#include <cstdint>

#define C_DIM 256
#define EPS 1e-5f

typedef __attribute__((ext_vector_type(8))) short short8;
typedef __attribute__((ext_vector_type(4))) float f32x4;

__device__ __forceinline__ ushort f2bf(float f) {
  uint32_t u = __float_as_uint(f);
  u = (u + 0x7fffu + ((u >> 16) & 1u)) >> 16;
  return (ushort)u;
}
__device__ __forceinline__ float bflo(uint32_t p) { return __uint_as_float(p << 16); }
__device__ __forceinline__ float bfhi(uint32_t p) { return __uint_as_float(p & 0xffff0000u); }

// ---------------- setup kernels ----------------
__global__ void k_count(const int* __restrict__ col, int E, int* cnt) {
  int e = blockIdx.x * blockDim.x + threadIdx.x;
  if (e < E) atomicAdd(&cnt[col[e]], 1);
}

// reads cnt -> isd, then zeroes cnt so it can be reused as the fill cursor
__global__ void k_isd(int* cnt, float* isd, int n) {
  int i = blockIdx.x * blockDim.x + threadIdx.x;
  if (i < n) { isd[i] = rsqrtf((float)(cnt[i] + 1)); cnt[i] = 0; }
}

__global__ void k_scan1(const int* __restrict__ cnt, int* excl, int* bsum, int n) {
  __shared__ int s[1024];
  int i = blockIdx.x * 1024 + threadIdx.x;
  int v = (i < n) ? cnt[i] : 0;
  s[threadIdx.x] = v;
  __syncthreads();
  for (int off = 1; off < 1024; off <<= 1) {
    int t = (threadIdx.x >= off) ? s[threadIdx.x - off] : 0;
    __syncthreads();
    s[threadIdx.x] += t;
    __syncthreads();
  }
  if (i < n) excl[i] = s[threadIdx.x] - v;
  if (threadIdx.x == 1023) bsum[blockIdx.x] = s[1023];
}

__global__ void k_scan2(int* bsum, int nb) {
  __shared__ int s[1024];
  int v = (threadIdx.x < nb) ? bsum[threadIdx.x] : 0;
  s[threadIdx.x] = v;
  __syncthreads();
  for (int off = 1; off < 1024; off <<= 1) {
    int t = (threadIdx.x >= off) ? s[threadIdx.x - off] : 0;
    __syncthreads();
    s[threadIdx.x] += t;
    __syncthreads();
  }
  if (threadIdx.x < nb) bsum[threadIdx.x] = s[threadIdx.x] - v;
}

__global__ void k_scan3(int* excl, const int* __restrict__ bsum, int n, int E) {
  int i = blockIdx.x * 1024 + threadIdx.x;
  if (i < n) excl[i] += bsum[blockIdx.x];
  if (i == 0) excl[n] = E;
}

// packed edge record: .x = src node, .y = fp32 bits of norm
__global__ void k_fill(const int* __restrict__ row, const int* __restrict__ col, int E,
                       const int* __restrict__ row_ptr, int* cursor,
                       const float* __restrict__ isd, int2* __restrict__ edat) {
  int e = blockIdx.x * blockDim.x + threadIdx.x;
  if (e < E) {
    int d = col[e], s = row[e];
    int p = row_ptr[d] + atomicAdd(&cursor[d], 1);
    edat[p] = make_int2(s, __float_as_int(isd[s] * isd[d]));
  }
}

__global__ void k_cvt_x(const float* __restrict__ x, ushort* __restrict__ xb, int n4) {
  int i = blockIdx.x * blockDim.x + threadIdx.x;
  if (i < n4) {
    float4 v = ((const float4*)x)[i];
    ushort4 o;
    o.x = f2bf(v.x); o.y = f2bf(v.y); o.z = f2bf(v.z); o.w = f2bf(v.w);
    ((ushort4*)xb)[i] = o;
  }
}

// W [K][N] fp32 -> Wt [N][K] bf16, for both layer weights
__global__ void k_cvt_w(const float* __restrict__ W1, const float* __restrict__ W2,
                        ushort* __restrict__ Wt1, ushort* __restrict__ Wt2) {
  int i = blockIdx.x * blockDim.x + threadIdx.x;  // output index [n][k]
  int n = i >> 8, k = i & 255;
  Wt1[i] = f2bf(W1[k * 256 + n]);
  Wt2[i] = f2bf(W2[k * 256 + n]);
}

// ---------------- bf16 MFMA GEMM: Cb[M,256] = A[M,256] @ Wt^T ----------------
__global__ __launch_bounds__(256) void k_gemm_bf16(const ushort* __restrict__ A,
                                                   const ushort* __restrict__ Wt,
                                                   ushort* __restrict__ Cb, int M) {
  __shared__ ushort As[128 * 64];
  __shared__ ushort Bs[128 * 64];
  const int tid = threadIdx.x;
  const int wave = tid >> 6, lane = tid & 63;
  const int bm = blockIdx.x * 128;
  const int bn = blockIdx.y * 128;
  const int wm = (wave >> 1) * 64, wn = (wave & 1) * 64;

  f32x4 acc[4][4] = {};

  const int r_off = lane >> 3;  // 0..7 rows per 1KB staging inst
  const int cc = lane & 7;      // 16B chunk slot within row

  for (int k0 = 0; k0 < C_DIM; k0 += 64) {
#pragma unroll
    for (int j = 0; j < 4; j++) {
      int rl = wave * 32 + j * 8 + r_off;  // tile row 0..127
      int c = cc ^ (rl & 7);               // swizzled source chunk
      int gm = bm + rl; if (gm >= M) gm = M - 1;
      const ushort* ga = &A[(size_t)gm * C_DIM + k0 + c * 8];
      ushort* la = &As[(size_t)(wave * 32 + j * 8) * 64];
      __builtin_amdgcn_global_load_lds((const __attribute__((address_space(1))) void*)ga,
                                       (__attribute__((address_space(3))) void*)la, 16, 0, 0);
      const ushort* gb = &Wt[(size_t)(bn + rl) * C_DIM + k0 + c * 8];
      ushort* lb = &Bs[(size_t)(wave * 32 + j * 8) * 64];
      __builtin_amdgcn_global_load_lds((const __attribute__((address_space(1))) void*)gb,
                                       (__attribute__((address_space(3))) void*)lb, 16, 0, 0);
    }
    __syncthreads();
#pragma unroll
    for (int s = 0; s < 2; s++) {
      short8 af[4], bfr[4];
#pragma unroll
      for (int t = 0; t < 4; t++) {
        int ra = wm + t * 16 + (lane & 15);
        int ca = s * 4 + (lane >> 4);
        af[t] = *(const short8*)&As[ra * 64 + ((ca ^ (ra & 7)) << 3)];
        int rb = wn + t * 16 + (lane & 15);
        bfr[t] = *(const short8*)&Bs[rb * 64 + ((ca ^ (rb & 7)) << 3)];
      }
#pragma unroll
      for (int mt = 0; mt < 4; mt++)
#pragma unroll
        for (int nt = 0; nt < 4; nt++)
          acc[mt][nt] = __builtin_amdgcn_mfma_f32_16x16x32_bf16(af[mt], bfr[nt], acc[mt][nt], 0, 0, 0);
    }
    __syncthreads();
  }

  // epilogue: C/D layout col=lane&15, row=(lane>>4)*4+reg (m89-verified)
#pragma unroll
  for (int mt = 0; mt < 4; mt++) {
#pragma unroll
    for (int nt = 0; nt < 4; nt++) {
      int col = bn + wn + nt * 16 + (lane & 15);
      int row0 = bm + wm + mt * 16 + ((lane >> 4) << 2);
#pragma unroll
      for (int r = 0; r < 4; r++) {
        int row = row0 + r;
        if (row < M) Cb[(size_t)row * C_DIM + col] = f2bf(acc[mt][nt][r]);
      }
    }
  }
}

// ---------------- fused aggregate(bf16 gather) + bias + LN + ReLU ----------------
__global__ __launch_bounds__(256) void k_agg_ln(const ushort* __restrict__ xwb,
    const int2* __restrict__ edat, const int* __restrict__ row_ptr,
    const float* __restrict__ isd,
    const float* __restrict__ bias, const float* __restrict__ gamma,
    const float* __restrict__ beta, float* __restrict__ out,
    ushort* __restrict__ outb, int n) {
  int i = blockIdx.x * 4 + (threadIdx.x >> 6);
  int lane = threadIdx.x & 63;
  if (i >= n) return;
  const uint2* xw2 = (const uint2*)xwb;  // 8B = 4 bf16 channels per lane

  float si = isd[i];
  float sn = si * si;
  uint2 p = xw2[(size_t)i * 64 + lane];
  float a0 = bflo(p.x) * sn, a1 = bfhi(p.x) * sn;
  float a2 = bflo(p.y) * sn, a3 = bfhi(p.y) * sn;

  int e0 = row_ptr[i], e1 = row_ptr[i + 1];
  int e = e0;
  // 4-deep unroll: 4 independent 512B row-gathers in flight per wave
  for (; e + 3 < e1; e += 4) {
    int2 ed0 = edat[e], ed1 = edat[e + 1], ed2 = edat[e + 2], ed3 = edat[e + 3];
    uint2 v0 = xw2[(size_t)ed0.x * 64 + lane];
    uint2 v1 = xw2[(size_t)ed1.x * 64 + lane];
    uint2 v2 = xw2[(size_t)ed2.x * 64 + lane];
    uint2 v3 = xw2[(size_t)ed3.x * 64 + lane];
    float w0 = __int_as_float(ed0.y), w1 = __int_as_float(ed1.y);
    float w2 = __int_as_float(ed2.y), w3 = __int_as_float(ed3.y);
    a0 += bflo(v0.x) * w0 + bflo(v1.x) * w1 + bflo(v2.x) * w2 + bflo(v3.x) * w3;
    a1 += bfhi(v0.x) * w0 + bfhi(v1.x) * w1 + bfhi(v2.x) * w2 + bfhi(v3.x) * w3;
    a2 += bflo(v0.y) * w0 + bflo(v1.y) * w1 + bflo(v2.y) * w2 + bflo(v3.y) * w3;
    a3 += bfhi(v0.y) * w0 + bfhi(v1.y) * w1 + bfhi(v2.y) * w2 + bfhi(v3.y) * w3;
  }
  for (; e < e1; e++) {
    int2 ed = edat[e];
    float w0 = __int_as_float(ed.y);
    uint2 v0 = xw2[(size_t)ed.x * 64 + lane];
    a0 += bflo(v0.x) * w0; a1 += bfhi(v0.x) * w0;
    a2 += bflo(v0.y) * w0; a3 += bfhi(v0.y) * w0;
  }

  float4 bv = ((const float4*)bias)[lane];
  a0 += bv.x; a1 += bv.y; a2 += bv.z; a3 += bv.w;

  float sum = a0 + a1 + a2 + a3;
  float sq = a0 * a0 + a1 * a1 + a2 * a2 + a3 * a3;
#pragma unroll
  for (int off = 32; off >= 1; off >>= 1) {
    sum += __shfl_xor(sum, off, 64);
    sq += __shfl_xor(sq, off, 64);
  }
  float mu = sum * (1.0f / C_DIM);
  float var = sq * (1.0f / C_DIM) - mu * mu;
  float rs = rsqrtf(var + EPS);

  float4 g = ((const float4*)gamma)[lane];
  float4 bt = ((const float4*)beta)[lane];
  float4 o;
  o.x = fmaxf((a0 - mu) * rs * g.x + bt.x, 0.0f);
  o.y = fmaxf((a1 - mu) * rs * g.y + bt.y, 0.0f);
  o.z = fmaxf((a2 - mu) * rs * g.z + bt.z, 0.0f);
  o.w = fmaxf((a3 - mu) * rs * g.w + bt.w, 0.0f);
  ((float4*)out)[(size_t)i * 64 + lane] = o;

  if (outb) {  // bf16 copy feeding next layer's GEMM
    uint2 q;
    q.x = (uint32_t)f2bf(o.x) | ((uint32_t)f2bf(o.y) << 16);
    q.y = (uint32_t)f2bf(o.z) | ((uint32_t)f2bf(o.w) << 16);
    ((uint2*)outb)[(size_t)i * 64 + lane] = q;
  }
}

// ---------------- host ----------------
extern "C" void kernel_launch(void* const* d_in, const int* in_sizes, int n_in,
                              void* d_out, int out_size, void* d_ws, size_t ws_size,
                              hipStream_t stream) {
  const float* x = (const float*)d_in[0];
  const int* edges = (const int*)d_in[1];
  const float* W1 = (const float*)d_in[2];
  const float* b1 = (const float*)d_in[3];
  const float* W2 = (const float*)d_in[4];
  const float* b2 = (const float*)d_in[5];
  const float* gamma = (const float*)d_in[6];
  const float* beta = (const float*)d_in[7];

  int N = in_sizes[0] / C_DIM;
  int E = in_sizes[1] / 2;
  const int* row = edges;
  const int* col = edges + E;

  char* ws = (char*)d_ws;
  size_t off = 0;
  auto alloc = [&](size_t bytes) -> void* {
    void* p = ws + off;
    off = (off + bytes + 255) & ~(size_t)255;
    return p;
  };
  ushort* xwb = (ushort*)alloc((size_t)N * C_DIM * 2);  // GEMM output, bf16
  ushort* xb  = (ushort*)alloc((size_t)N * C_DIM * 2);  // layer-1 A; aliased as z1-bf16 after agg1
  ushort* Wt1 = (ushort*)alloc(65536 * 2);
  ushort* Wt2 = (ushort*)alloc(65536 * 2);
  int* cnt = (int*)alloc((size_t)N * 4);                 // reused as fill cursor
  float* isd = (float*)alloc((size_t)N * 4);
  int* row_ptr = (int*)alloc((size_t)(N + 1) * 4);
  int nb = (N + 1023) / 1024;
  int* bsum = (int*)alloc((size_t)nb * 4);
  int2* edat = (int2*)alloc((size_t)E * 8);              // packed (src, nrm)

  float* z1 = (float*)d_out;
  float* z2 = (float*)d_out + (size_t)N * C_DIM;

  // conversions
  int n4 = N * C_DIM / 4;
  k_cvt_x<<<(n4 + 255) / 256, 256, 0, stream>>>(x, xb, n4);
  k_cvt_w<<<256, 256, 0, stream>>>(W1, W2, Wt1, Wt2);

  // CSR build (shared by both layers)
  hipMemsetAsync(cnt, 0, (size_t)N * 4, stream);
  k_count<<<(E + 255) / 256, 256, 0, stream>>>(col, E, cnt);
  k_scan1<<<nb, 1024, 0, stream>>>(cnt, row_ptr, bsum, N);
  k_scan2<<<1, 1024, 0, stream>>>(bsum, nb);
  k_scan3<<<nb, 1024, 0, stream>>>(row_ptr, bsum, N, E);
  k_isd<<<(N + 255) / 256, 256, 0, stream>>>(cnt, isd, N);  // zeroes cnt -> cursor
  k_fill<<<(E + 255) / 256, 256, 0, stream>>>(row, col, E, row_ptr, cnt, isd, edat);

  dim3 ggrid((N + 127) / 128, 2);
  int agg_blocks = (N + 3) / 4;

  // layer 1
  k_gemm_bf16<<<ggrid, 256, 0, stream>>>(xb, Wt1, xwb, N);
  k_agg_ln<<<agg_blocks, 256, 0, stream>>>(xwb, edat, row_ptr, isd, b1, gamma, beta, z1, xb, N);
  // layer 2 (xb now holds z1 in bf16)
  k_gemm_bf16<<<ggrid, 256, 0, stream>>>(xb, Wt2, xwb, N);
  k_agg_ln<<<agg_blocks, 256, 0, stream>>>(xwb, edat, row_ptr, isd, b2, gamma, beta, z2, nullptr, N);
}